// Round 1
// baseline (686.412 us; speedup 1.0000x reference)
//
#include <hip/hip_runtime.h>
#include <cstdint>

// Problem constants (from reference): T_OBS=16, T_FUT=14, D=66
#define ROW  1056   // T_OBS * D        (floats per train_pose row)
#define VEL  990    // (T_OBS-1) * D    (velocity features)
#define FUT  924    // T_FUT * D        (floats per output row)

// ws layout: [0] unsigned long long packed best = (dist_bits<<32) | idx

__global__ void nn_init(unsigned long long* best) {
    if (threadIdx.x == 0 && blockIdx.x == 0)
        *best = 0xFFFFFFFFFFFFFFFFull;
}

__global__ __launch_bounds__(256) void nn_dist(const float* __restrict__ obs,
                                               const float* __restrict__ train,
                                               int N,
                                               unsigned long long* best) {
    const int lane = threadIdx.x & 63;
    const int wave = threadIdx.x >> 6;
    const int wavesPerBlock = blockDim.x >> 6;            // 4
    const long long gwave   = (long long)blockIdx.x * wavesPerBlock + wave;
    const long long wstride = (long long)gridDim.x * wavesPerBlock;

    // Query velocity for this lane's strided elements: i = lane + 64k.
    // k=0..14 are always in-bounds (max i = 63+896 = 959 < 990); k=15 is guarded.
    float qv[15];
    #pragma unroll
    for (int k = 0; k < 15; ++k) {
        int i = lane + 64 * k;
        qv[k] = obs[i + 66] - obs[i];
    }
    const int  i15    = lane + 960;
    const bool has15  = (i15 < VEL);                      // lanes 0..29
    float qv15 = has15 ? (obs[i15 + 66] - obs[i15]) : 0.0f;

    float bestDist = __builtin_inff();
    int   bestIdx  = 0;

    for (long long n = gwave; n < N; n += wstride) {
        const float* __restrict__ row = train + n * ROW;
        float sum = 0.0f;
        #pragma unroll
        for (int k = 0; k < 15; ++k) {
            int i = lane + 64 * k;
            float d = row[i + 66] - row[i] - qv[k];
            sum += d * d;
        }
        if (has15) {
            float d = row[i15 + 66] - row[i15] - qv15;
            sum += d * d;
        }
        // wave-wide butterfly sum (64 lanes)
        #pragma unroll
        for (int off = 32; off > 0; off >>= 1)
            sum += __shfl_xor(sum, off, 64);
        if (sum < bestDist) { bestDist = sum; bestIdx = (int)n; }
    }

    // pack (dist,idx): non-negative fp32 bits are order-preserving; min over
    // the packed key tie-breaks to the smallest index == jnp.argmin semantics
    unsigned long long key =
        ((unsigned long long)__float_as_uint(bestDist) << 32) | (unsigned)bestIdx;

    __shared__ unsigned long long wbest[8];
    if (lane == 0) wbest[wave] = key;
    __syncthreads();
    if (threadIdx.x == 0) {
        unsigned long long k0 = wbest[0];
        for (int w = 1; w < wavesPerBlock; ++w)
            k0 = (wbest[w] < k0) ? wbest[w] : k0;
        atomicMin(best, k0);                               // one atomic per block
    }
}

__global__ void nn_gather(const unsigned long long* best,
                          const float* __restrict__ fut,
                          float* __restrict__ out) {
    const int idx = (int)(unsigned)(*best & 0xFFFFFFFFull);
    const float4* __restrict__ src = (const float4*)(fut + (long long)idx * FUT);
    float4* __restrict__ dst = (float4*)out;
    for (int i = threadIdx.x; i < FUT / 4; i += blockDim.x)  // 231 x 16B
        dst[i] = src[i];
}

extern "C" void kernel_launch(void* const* d_in, const int* in_sizes, int n_in,
                              void* d_out, int out_size, void* d_ws, size_t ws_size,
                              hipStream_t stream) {
    const float* obs   = (const float*)d_in[0];   // (1, 16, 66)   = 1056
    const float* train = (const float*)d_in[1];   // (N, 16, 66)
    const float* fut   = (const float*)d_in[2];   // (N, 14, 66)
    float* out = (float*)d_out;                   // (1, 14, 66)   = 924
    const int N = in_sizes[1] / ROW;              // 100000

    unsigned long long* best = (unsigned long long*)d_ws;

    nn_init<<<1, 64, 0, stream>>>(best);
    // 2048 blocks x 256 thr = 8192 waves (~12 samples/wave); 8 blocks/CU
    nn_dist<<<2048, 256, 0, stream>>>(obs, train, N, best);
    nn_gather<<<1, 256, 0, stream>>>(best, fut, out);
}

// Round 2
// 685.603 us; speedup vs baseline: 1.0012x; 1.0012x over previous
//
#include <hip/hip_runtime.h>
#include <cstdint>

// Problem constants: T_OBS=16, T_FUT=14, D=66
#define ROW   1056   // floats per train_pose row
#define ROW2  528    // float2 per train_pose row
#define VEL2  495    // float2 velocity elements ((16-1)*66/2)
#define FUT   924    // floats per output row

__global__ void nn_init(unsigned long long* best) {
    if (threadIdx.x == 0 && blockIdx.x == 0)
        *best = 0xFFFFFFFFFFFFFFFFull;
}

// block=256 (4 waves); __launch_bounds__(256,4) caps VGPR at 128 -> 16 waves/CU,
// each wave keeps 32 dwordx2 loads (16 KB) in flight per row-pair iteration.
__global__ __launch_bounds__(256, 4) void nn_dist(const float* __restrict__ obs,
                                                  const float* __restrict__ train,
                                                  int N,
                                                  unsigned long long* best) {
    const int lane = threadIdx.x & 63;
    const int wave = threadIdx.x >> 6;
    const int wpb  = blockDim.x >> 6;                     // 4
    const long long gwave   = (long long)blockIdx.x * wpb + wave;
    const long long wstride = (long long)gridDim.x * wpb; // 8192

    const float2* __restrict__ obs2 = (const float2*)obs;
    const float2* __restrict__ tr2  = (const float2*)train;

    // Query velocity diffs, float2 granularity: q[k] for j = lane + 64k.
    // k=0..6 always in-bounds (max j = 447 < 495); k=7 valid for lane < 47.
    const bool t7 = (lane < (VEL2 - 448));                // lane < 47
    float qx[8], qy[8];
    #pragma unroll
    for (int k = 0; k < 7; ++k) {
        int j = lane + 64 * k;
        float2 a = obs2[j], b = obs2[j + 33];
        qx[k] = b.x - a.x;  qy[k] = b.y - a.y;
    }
    if (t7) {
        int j = lane + 448;
        float2 a = obs2[j], b = obs2[j + 33];
        qx[7] = b.x - a.x;  qy[7] = b.y - a.y;
    } else { qx[7] = 0.f; qy[7] = 0.f; }

    unsigned long long bestKey = 0xFFFFFFFFFFFFFFFFull;

    // Two rows per iteration: two independent load batches + reduce chains.
    for (long long n = 2 * gwave; n < N; n += 2 * wstride) {
        const bool have1 = (n + 1 < N);                   // always true for even N
        const float2* __restrict__ r0 = tr2 + n * ROW2;
        const float2* __restrict__ r1 = have1 ? (r0 + ROW2) : r0;

        float s0 = 0.f, s1 = 0.f;
        #pragma unroll
        for (int k = 0; k < 7; ++k) {
            int j = lane + 64 * k;
            float2 a0 = r0[j], b0 = r0[j + 33];
            float2 a1 = r1[j], b1 = r1[j + 33];
            float dx0 = b0.x - a0.x - qx[k], dy0 = b0.y - a0.y - qy[k];
            float dx1 = b1.x - a1.x - qx[k], dy1 = b1.y - a1.y - qy[k];
            s0 += dx0 * dx0 + dy0 * dy0;
            s1 += dx1 * dx1 + dy1 * dy1;
        }
        if (t7) {
            int j = lane + 448;
            float2 a0 = r0[j], b0 = r0[j + 33];
            float2 a1 = r1[j], b1 = r1[j + 33];
            float dx0 = b0.x - a0.x - qx[7], dy0 = b0.y - a0.y - qy[7];
            float dx1 = b1.x - a1.x - qx[7], dy1 = b1.y - a1.y - qy[7];
            s0 += dx0 * dx0 + dy0 * dy0;
            s1 += dx1 * dx1 + dy1 * dy1;
        }

        // two independent 64-lane butterfly sums (chains overlap)
        #pragma unroll
        for (int off = 32; off > 0; off >>= 1) {
            s0 += __shfl_xor(s0, off, 64);
            s1 += __shfl_xor(s1, off, 64);
        }

        // packed (dist_bits<<32)|idx: min == argmin with smallest-index ties
        unsigned long long k0 =
            ((unsigned long long)__float_as_uint(s0) << 32) | (unsigned)n;
        if (k0 < bestKey) bestKey = k0;
        if (have1) {
            unsigned long long k1 =
                ((unsigned long long)__float_as_uint(s1) << 32) | (unsigned)(n + 1);
            if (k1 < bestKey) bestKey = k1;
        }
    }

    __shared__ unsigned long long wbest[4];
    if (lane == 0) wbest[wave] = bestKey;
    __syncthreads();
    if (threadIdx.x == 0) {
        unsigned long long k0 = wbest[0];
        for (int w = 1; w < wpb; ++w)
            k0 = (wbest[w] < k0) ? wbest[w] : k0;
        atomicMin(best, k0);                              // one atomic per block
    }
}

__global__ void nn_gather(const unsigned long long* best,
                          const float* __restrict__ fut,
                          float* __restrict__ out) {
    const int idx = (int)(unsigned)(*best & 0xFFFFFFFFull);
    const float4* __restrict__ src = (const float4*)(fut + (long long)idx * FUT);
    float4* __restrict__ dst = (float4*)out;
    for (int i = threadIdx.x; i < FUT / 4; i += blockDim.x)  // 231 x 16B
        dst[i] = src[i];
}

extern "C" void kernel_launch(void* const* d_in, const int* in_sizes, int n_in,
                              void* d_out, int out_size, void* d_ws, size_t ws_size,
                              hipStream_t stream) {
    const float* obs   = (const float*)d_in[0];   // (1, 16, 66)
    const float* train = (const float*)d_in[1];   // (N, 16, 66)
    const float* fut   = (const float*)d_in[2];   // (N, 14, 66)
    float* out = (float*)d_out;                   // (1, 14, 66)
    const int N = in_sizes[1] / ROW;              // 100000

    unsigned long long* best = (unsigned long long*)d_ws;

    nn_init<<<1, 64, 0, stream>>>(best);
    nn_dist<<<2048, 256, 0, stream>>>(obs, train, N, best);
    nn_gather<<<1, 256, 0, stream>>>(best, fut, out);
}